// Round 1
// baseline (375.714 us; speedup 1.0000x reference)
//
#include <hip/hip_runtime.h>

#define GROUPSIZE 128
#define IN_F 4096
#define OUT_F 11008
#define TOKENS 512

#define BM 128
#define BN 128
#define BK 64
#define NTHREADS 256
#define NT (IN_F / BK)   // 64 K-iterations

typedef _Float16 half8 __attribute__((ext_vector_type(8)));
typedef float    f32x4 __attribute__((ext_vector_type(4)));
typedef float    fvec4 __attribute__((ext_vector_type(4)));
typedef int      ivec4 __attribute__((ext_vector_type(4)));

// halfword-index swizzle within a [rows][64] fp16 tile: spreads the
// 128B row stride across banks so frag ds_read_b128 is conflict-free.
__device__ __forceinline__ int swz(int r, int k) {
    return ((r << 6) + k) ^ ((r & 7) << 3);
}

__global__ __launch_bounds__(NTHREADS, 2)
void qlinear_a16w4_kernel(const float* __restrict__ x,
                          const int*   __restrict__ qw,
                          const float* __restrict__ scales,
                          const float* __restrict__ zeros,
                          const float* __restrict__ bias,
                          float*       __restrict__ out)
{
    const int tid = threadIdx.x;
    const int n0 = blockIdx.x * BN;
    const int m0 = blockIdx.y * BM;

    // staging roles: each thread owns one tile row (0..127), half h (0..1)
    const int srow = tid >> 1;
    const int h    = tid & 1;

    const float* xg = x  + (size_t)(m0 + srow) * IN_F + h * 32;
    const int*   qg = qw + (size_t)(n0 + srow) * (IN_F / 2) + h * 16;
    const int    gbase = (n0 + srow) * (IN_F / GROUPSIZE);

    __shared__ __align__(16) _Float16 As[BM * BK];
    __shared__ __align__(16) _Float16 Bs[BN * BK];

    // MFMA roles
    const int wave = tid >> 6;
    const int lane = tid & 63;
    const int wr = (wave >> 1) * 64;      // wave row offset in tile
    const int wc = (wave & 1) * 64;       // wave col offset in tile
    const int lr  = lane & 15;
    const int lk8 = (lane >> 4) * 8;
    const int lk4 = (lane >> 4) * 4;

    f32x4 acc[4][4];
#pragma unroll
    for (int i = 0; i < 4; ++i)
#pragma unroll
        for (int j = 0; j < 4; ++j)
            acc[i][j] = (f32x4){0.f, 0.f, 0.f, 0.f};

    // ---- prologue: stage tile 0 into registers ----
    fvec4 a_st[8];
    ivec4 b_st[4];
#pragma unroll
    for (int i = 0; i < 8; ++i) a_st[i] = ((const fvec4*)xg)[i];
#pragma unroll
    for (int i = 0; i < 4; ++i) b_st[i] = ((const ivec4*)qg)[i];
    float s_cur = scales[gbase];
    float z_cur = zeros[gbase];

    for (int t = 0; t < NT; ++t) {
        // ---- convert staged regs -> LDS ----
        {
            const float s = s_cur;
            const float z = z_cur;
#pragma unroll
            for (int i = 0; i < 4; ++i) {
                fvec4 v0 = a_st[2 * i], v1 = a_st[2 * i + 1];
                half8 hv;
                hv[0] = (_Float16)v0[0]; hv[1] = (_Float16)v0[1];
                hv[2] = (_Float16)v0[2]; hv[3] = (_Float16)v0[3];
                hv[4] = (_Float16)v1[0]; hv[5] = (_Float16)v1[1];
                hv[6] = (_Float16)v1[2]; hv[7] = (_Float16)v1[3];
                *(half8*)(&As[swz(srow, h * 32 + 8 * i)]) = hv;
            }
#pragma unroll
            for (int i = 0; i < 4; ++i) {
                ivec4 qv = b_st[i];
                half8 wv;
#pragma unroll
                for (int e = 0; e < 4; ++e) {
                    int q = qv[e];
                    float fh = (float)((q >> 4) & 15);
                    float fl = (float)(q & 15);
                    wv[2 * e]     = (_Float16)((fh - z) * s);
                    wv[2 * e + 1] = (_Float16)((fl - z) * s);
                }
                *(half8*)(&Bs[swz(srow, h * 32 + 8 * i)]) = wv;
            }
        }
        __syncthreads();

        // ---- issue next tile's global loads (hide under MFMA) ----
        float s_nxt = s_cur, z_nxt = z_cur;
        if (t + 1 < NT) {
            const float* xn = xg + (t + 1) * BK;
            const int*   qn = qg + (t + 1) * (BK / 2);
#pragma unroll
            for (int i = 0; i < 8; ++i) a_st[i] = ((const fvec4*)xn)[i];
#pragma unroll
            for (int i = 0; i < 4; ++i) b_st[i] = ((const ivec4*)qn)[i];
            const int gn = gbase + ((t + 1) >> 1);
            s_nxt = scales[gn];
            z_nxt = zeros[gn];
        }

        // ---- MFMA over current LDS tile ----
#pragma unroll
        for (int kk = 0; kk < 2; ++kk) {
            half8 af[4], bf[4];
#pragma unroll
            for (int i = 0; i < 4; ++i)
                af[i] = *(const half8*)(&As[swz(wr + i * 16 + lr, kk * 32 + lk8)]);
#pragma unroll
            for (int j = 0; j < 4; ++j)
                bf[j] = *(const half8*)(&Bs[swz(wc + j * 16 + lr, kk * 32 + lk8)]);
#pragma unroll
            for (int i = 0; i < 4; ++i)
#pragma unroll
                for (int j = 0; j < 4; ++j)
                    acc[i][j] = __builtin_amdgcn_mfma_f32_16x16x32_f16(
                        af[i], bf[j], acc[i][j], 0, 0, 0);
        }
        __syncthreads();

        s_cur = s_nxt;
        z_cur = z_nxt;
    }

    // ---- epilogue: bias + store ----
#pragma unroll
    for (int j = 0; j < 4; ++j) {
        const int col = n0 + wc + j * 16 + lr;
        const float bv = bias[col];
#pragma unroll
        for (int i = 0; i < 4; ++i) {
            const int rbase = m0 + wr + i * 16 + lk4;
#pragma unroll
            for (int r = 0; r < 4; ++r)
                out[(size_t)(rbase + r) * OUT_F + col] = acc[i][j][r] + bv;
        }
    }
}

extern "C" void kernel_launch(void* const* d_in, const int* in_sizes, int n_in,
                              void* d_out, int out_size, void* d_ws, size_t ws_size,
                              hipStream_t stream) {
    const float* x      = (const float*)d_in[0];
    const int*   qw     = (const int*)d_in[1];
    const float* scales = (const float*)d_in[2];
    const float* zeros  = (const float*)d_in[3];
    const float* bias   = (const float*)d_in[4];
    float*       out    = (float*)d_out;

    dim3 grid(OUT_F / BN, TOKENS / BM);   // 86 x 4
    qlinear_a16w4_kernel<<<grid, NTHREADS, 0, stream>>>(x, qw, scales, zeros, bias, out);
}

// Round 2
// 312.074 us; speedup vs baseline: 1.2039x; 1.2039x over previous
//
#include <hip/hip_runtime.h>

#define GROUPSIZE 128
#define IN_F 4096
#define OUT_F 11008
#define TOKENS 512
#define N_GROUPS (OUT_F * IN_F / GROUPSIZE)  // 352256

#define BM 64
#define BN 128
#define BK 64
#define NTHREADS 256
#define NT (IN_F / BK)   // 64 K-steps

typedef _Float16 half8  __attribute__((ext_vector_type(8)));
typedef _Float16 half2v __attribute__((ext_vector_type(2)));
typedef float    f32x4  __attribute__((ext_vector_type(4)));
typedef int      ivec4  __attribute__((ext_vector_type(4)));

// halfword-index swizzle within [rows][64]-halfword tile (row = 128 B):
// XOR granule (16B unit) by row&7 -> frag ds_read_b128 is bank-uniform.
__device__ __forceinline__ int swz(int r, int k) {
    return ((r << 6) + k) ^ ((r & 7) << 3);
}

__device__ __forceinline__ void glds16(const _Float16* g, _Float16* l) {
    __builtin_amdgcn_global_load_lds(
        (const __attribute__((address_space(1))) void*)g,
        (__attribute__((address_space(3))) void*)l, 16, 0, 0);
}

// ---------- pre-kernel 1: x fp32 -> fp16 (x is reused 86x; convert once) ----------
__global__ __launch_bounds__(256)
void cvt_x_kernel(const float* __restrict__ x, _Float16* __restrict__ x16) {
    size_t i = ((size_t)blockIdx.x * 256 + threadIdx.x) * 8;
    f32x4 a = *(const f32x4*)(x + i);
    f32x4 b = *(const f32x4*)(x + i + 4);
    half8 h;
    h[0]=(_Float16)a[0]; h[1]=(_Float16)a[1]; h[2]=(_Float16)a[2]; h[3]=(_Float16)a[3];
    h[4]=(_Float16)b[0]; h[5]=(_Float16)b[1]; h[6]=(_Float16)b[2]; h[7]=(_Float16)b[3];
    *(half8*)(x16 + i) = h;
}

// ---------- pre-kernel 2: pack (S, -(64+z)*S) as fp16x2 duplicated pairs ----------
__global__ __launch_bounds__(256)
void szpack_kernel(const float* __restrict__ s, const float* __restrict__ z,
                   uint2* __restrict__ szp) {
    int g = blockIdx.x * 256 + threadIdx.x;
    if (g >= N_GROUPS) return;
    _Float16 S = (_Float16)s[g];
    _Float16 B = (_Float16)(-(64.0f + z[g]) * (float)S);
    unsigned short su = __builtin_bit_cast(unsigned short, S);
    unsigned short bu = __builtin_bit_cast(unsigned short, B);
    uint2 r;
    r.x = ((unsigned)su << 16) | su;
    r.y = ((unsigned)bu << 16) | bu;
    szp[g] = r;
}

// dequant one int32 "byte" (2 nibbles) pair-wise: fp16(64+n) via OR, then pk_fma
__device__ __forceinline__ half8 dq8(ivec4 q, uint2 sz) {
    half2v S  = __builtin_bit_cast(half2v, sz.x);
    half2v Bv = __builtin_bit_cast(half2v, sz.y);
    half8 r;
#pragma unroll
    for (int e = 0; e < 4; ++e) {
        unsigned qq = (unsigned)q[e];
        unsigned u = ((qq & 0xF0u) | ((qq << 20) & 0x00F00000u)) | 0x54005400u;
        half2v h = __builtin_bit_cast(half2v, u);
        half2v w = h * S + Bv;          // v_pk_fma_f16: (64+n)*S - (64+z)*S = (n-z)*S
        r[2*e]   = w[0];                // hi nibble -> even k
        r[2*e+1] = w[1];                // lo nibble -> odd k
    }
    return r;
}

__global__ __launch_bounds__(NTHREADS, 3)
void qlinear_main(const _Float16* __restrict__ x16,
                  const int*   __restrict__ qw,
                  const uint2* __restrict__ szp,
                  const float* __restrict__ bias,
                  float*       __restrict__ out)
{
    __shared__ __align__(16) _Float16 As[2][BM * BK];
    __shared__ __align__(16) _Float16 Bs[2][BN * BK];

    const int tid = threadIdx.x;
    const int n0 = blockIdx.x * BN;
    const int m0 = blockIdx.y * BM;
    const int wv = tid >> 6, ln = tid & 63;

    // ---- B staging role: thread owns row brow, k-half bh (32 k = 16 int32) ----
    const int brow = tid & 127;
    const int bh   = tid >> 7;
    const int* qg = qw + (size_t)(n0 + brow) * (IN_F / 2) + bh * 16;
    const int szbase = (n0 + brow) * (IN_F / GROUPSIZE);

    // ---- A staging role (global_load_lds, pre-swizzled source) ----
    const int ar  = wv * 16 + (ln >> 3);            // + 8*i per instruction
    const int gsw = (ln & 7) ^ ((ln >> 3) & 7);     // inverse swizzle on source
    const _Float16* ag = x16 + (size_t)(m0 + ar) * IN_F + gsw * 8;

    // ---- MFMA role: wave (wr,wc) owns 32x64 of the 64x128 tile ----
    const int wr = (wv >> 1) * 32, wc = (wv & 1) * 64;
    const int lr = ln & 15, lk8 = (ln >> 4) * 8, lk4 = (ln >> 4) * 4;

    f32x4 acc[2][4];
#pragma unroll
    for (int i = 0; i < 2; ++i)
#pragma unroll
        for (int j = 0; j < 4; ++j)
            acc[i][j] = (f32x4){0.f, 0.f, 0.f, 0.f};

#define LOAD_Q(qs, szs, tt) do {                                   \
        const ivec4* qp = (const ivec4*)(qg + (tt) * 32);          \
        qs[0] = qp[0]; qs[1] = qp[1]; qs[2] = qp[2]; qs[3] = qp[3];\
        szs = szp[szbase + ((tt) >> 1)];                           \
    } while (0)

#define STAGE_A(tt, buf) do {                                      \
        const _Float16* gp = ag + (size_t)(tt) * 64;               \
        glds16(gp,             &As[buf][wv * 1024]);               \
        glds16(gp + 8 * IN_F,  &As[buf][wv * 1024 + 512]);         \
    } while (0)

#define DQ_STORE(qs, szs, buf) do {                                        \
        *(half8*)&Bs[buf][swz(brow, bh * 32 + 0)]  = dq8(qs[0], szs);      \
        *(half8*)&Bs[buf][swz(brow, bh * 32 + 8)]  = dq8(qs[1], szs);      \
        *(half8*)&Bs[buf][swz(brow, bh * 32 + 16)] = dq8(qs[2], szs);      \
        *(half8*)&Bs[buf][swz(brow, bh * 32 + 24)] = dq8(qs[3], szs);      \
    } while (0)

    auto mfma_phase = [&](int buf) {
#pragma unroll
        for (int kk = 0; kk < 2; ++kk) {
            half8 af[2], bf[4];
#pragma unroll
            for (int i = 0; i < 2; ++i)
                af[i] = *(const half8*)&As[buf][swz(wr + i * 16 + lr, kk * 32 + lk8)];
#pragma unroll
            for (int j = 0; j < 4; ++j)
                bf[j] = *(const half8*)&Bs[buf][swz(wc + j * 16 + lr, kk * 32 + lk8)];
#pragma unroll
            for (int i = 0; i < 2; ++i)
#pragma unroll
                for (int j = 0; j < 4; ++j)
                    acc[i][j] = __builtin_amdgcn_mfma_f32_16x16x32_f16(
                        af[i], bf[j], acc[i][j], 0, 0, 0);
        }
    };

    // ---- prologue: regs hold tiles 0,1; LDS buf0 holds tile 0 ----
    ivec4 qA[4], qB[4];
    uint2 szA, szB;
    LOAD_Q(qA, szA, 0);
    LOAD_Q(qB, szB, 1);
    STAGE_A(0, 0);
    DQ_STORE(qA, szA, 0);
    __syncthreads();   // implicit vmcnt(0): glds A(0) + loads drained

    // ---- main loop: 1 barrier/K-step; B regs 2-deep, A glds 1-deep ----
    for (int t = 0; t < NT; t += 2) {
        {   // iter t (cur = 0)
            const int tl = (t + 2 < NT) ? t + 2 : NT - 1;
            LOAD_Q(qA, szA, tl);                       // tile t+2 -> regs (drains at barrier)
            STAGE_A((t + 1 < NT) ? t + 1 : NT - 1, 1); // A tile t+1 -> LDS
            DQ_STORE(qB, szB, 1);                      // dequant tile t+1 (regs 1 iter old)
            mfma_phase(0);                             // compute tile t
            __syncthreads();
        }
        {   // iter t+1 (cur = 1)
            const int tl = (t + 3 < NT) ? t + 3 : NT - 1;
            LOAD_Q(qB, szB, tl);
            STAGE_A((t + 2 < NT) ? t + 2 : NT - 1, 0);
            DQ_STORE(qA, szA, 0);
            mfma_phase(1);
            __syncthreads();
        }
    }

    // ---- epilogue ----
#pragma unroll
    for (int j = 0; j < 4; ++j) {
        const int col = n0 + wc + j * 16 + lr;
        const float bv = bias[col];
#pragma unroll
        for (int i = 0; i < 2; ++i) {
            const int rb = m0 + wr + i * 16 + lk4;
#pragma unroll
            for (int r = 0; r < 4; ++r)
                out[(size_t)(rb + r) * OUT_F + col] = acc[i][j][r] + bv;
        }
    }
#undef LOAD_Q
#undef STAGE_A
#undef DQ_STORE
}

extern "C" void kernel_launch(void* const* d_in, const int* in_sizes, int n_in,
                              void* d_out, int out_size, void* d_ws, size_t ws_size,
                              hipStream_t stream) {
    const float* x      = (const float*)d_in[0];
    const int*   qw     = (const int*)d_in[1];
    const float* scales = (const float*)d_in[2];
    const float* zeros  = (const float*)d_in[3];
    const float* bias   = (const float*)d_in[4];
    float*       out    = (float*)d_out;

    _Float16* x16 = (_Float16*)d_ws;                                   // 4 MB
    uint2*    szp = (uint2*)((char*)d_ws + (size_t)TOKENS * IN_F * 2); // 2.75 MB

    cvt_x_kernel<<<TOKENS * IN_F / (256 * 8), 256, 0, stream>>>(x, x16);
    szpack_kernel<<<(N_GROUPS + 255) / 256, 256, 0, stream>>>(scales, zeros, szp);

    dim3 grid(OUT_F / BN, TOKENS / BM);   // 86 x 8 = 688 blocks
    qlinear_main<<<grid, NTHREADS, 0, stream>>>(x16, qw, szp, bias, out);
}

// Round 3
// 255.032 us; speedup vs baseline: 1.4732x; 1.2237x over previous
//
#include <hip/hip_runtime.h>

#define GROUPSIZE 128
#define IN_F 4096
#define OUT_F 11008
#define TOKENS 512
#define N_GROUPS (OUT_F * IN_F / GROUPSIZE)  // 352256

#define BM 64
#define BN 128
#define BK 64
#define NTHREADS 256
#define NT (IN_F / BK)   // 64 K-steps

typedef _Float16 half8  __attribute__((ext_vector_type(8)));
typedef _Float16 half2v __attribute__((ext_vector_type(2)));
typedef float    f32x4  __attribute__((ext_vector_type(4)));
typedef int      ivec4  __attribute__((ext_vector_type(4)));

// halfword-index swizzle within [rows][64]-halfword tile (row = 128 B):
// XOR 16B-granule by row&7 -> frag ds_read_b128 is bank-uniform.
__device__ __forceinline__ int swz(int r, int k) {
    return ((r << 6) + k) ^ ((r & 7) << 3);
}

__device__ __forceinline__ void glds16(const _Float16* g, _Float16* l) {
    __builtin_amdgcn_global_load_lds(
        (const __attribute__((address_space(1))) void*)g,
        (__attribute__((address_space(3))) void*)l, 16, 0, 0);
}

// ---------- pre-kernel 1: x fp32 -> fp16 (x reused 86x; convert once) ----------
__global__ __launch_bounds__(256)
void cvt_x_kernel(const float* __restrict__ x, _Float16* __restrict__ x16) {
    size_t i = ((size_t)blockIdx.x * 256 + threadIdx.x) * 8;
    f32x4 a = *(const f32x4*)(x + i);
    f32x4 b = *(const f32x4*)(x + i + 4);
    half8 h;
    h[0]=(_Float16)a[0]; h[1]=(_Float16)a[1]; h[2]=(_Float16)a[2]; h[3]=(_Float16)a[3];
    h[4]=(_Float16)b[0]; h[5]=(_Float16)b[1]; h[6]=(_Float16)b[2]; h[7]=(_Float16)b[3];
    *(half8*)(x16 + i) = h;
}

// ---------- pre-kernel 2: pack (S, -(64+z)*S) as duplicated fp16 pairs ----------
__global__ __launch_bounds__(256)
void szpack_kernel(const float* __restrict__ s, const float* __restrict__ z,
                   uint2* __restrict__ szp) {
    int g = blockIdx.x * 256 + threadIdx.x;
    if (g >= N_GROUPS) return;
    _Float16 S = (_Float16)s[g];
    _Float16 B = (_Float16)(-(64.0f + z[g]) * (float)S);
    unsigned short su = __builtin_bit_cast(unsigned short, S);
    unsigned short bu = __builtin_bit_cast(unsigned short, B);
    uint2 r;
    r.x = ((unsigned)su << 16) | su;
    r.y = ((unsigned)bu << 16) | bu;
    szp[g] = r;
}

// dequant 4 int32-bytes (8 nibbles): fp16(64+n) via OR, then one pk_fma each
__device__ __forceinline__ half8 dq8(ivec4 q, uint2 sz) {
    half2v S  = __builtin_bit_cast(half2v, sz.x);
    half2v Bv = __builtin_bit_cast(half2v, sz.y);
    half8 r;
#pragma unroll
    for (int e = 0; e < 4; ++e) {
        unsigned qq = (unsigned)q[e];
        unsigned u = ((qq & 0xF0u) | ((qq << 20) & 0x00F00000u)) | 0x54005400u;
        half2v h = __builtin_bit_cast(half2v, u);
        half2v w = h * S + Bv;          // (64+n)*S - (64+z)*S = (n-z)*S
        r[2*e]   = w[0];                // hi nibble -> even k
        r[2*e+1] = w[1];                // lo nibble -> odd k
    }
    return r;
}

__global__ __launch_bounds__(NTHREADS, 3)
void qlinear_main(const _Float16* __restrict__ x16,
                  const int*   __restrict__ qw,
                  const uint2* __restrict__ szp,
                  const float* __restrict__ bias,
                  float*       __restrict__ out)
{
    __shared__ __align__(16) _Float16 As[2][BM * BK];
    __shared__ __align__(16) _Float16 Bs[2][BN * BK];

    const int tid = threadIdx.x;
    const int m0 = blockIdx.x * BM;   // 8 m-tiles -> one per XCD, co-scheduled
    const int n0 = blockIdx.y * BN;   // 86 n-tiles swept in lockstep -> q L3-shared
    const int wv = tid >> 6, ln = tid & 63;

    // ---- B staging role: 8 consecutive lanes cover 128 contiguous bytes of a row.
    // Thread: segment s (16B = 4 int32 = 8 weights) of rows r0+32j, j=0..3.
    const int s8 = tid & 7;           // segment within the row's K-step slice
    const int r0 = tid >> 3;          // 0..31
    const int* qg = qw + (size_t)(n0 + r0) * (IN_F / 2) + s8 * 4;
    const int szb = (n0 + r0) * (IN_F / GROUPSIZE);

    // ---- A staging role (global_load_lds, inverse-swizzled source) ----
    const int ar  = wv * 16 + (ln >> 3);
    const int gsw = (ln & 7) ^ ((ln >> 3) & 7);
    const _Float16* ag = x16 + (size_t)(m0 + ar) * IN_F + gsw * 8;

    // ---- MFMA role: wave (wr,wc) owns 32x64 of the 64x128 tile ----
    const int wr = (wv >> 1) * 32, wc = (wv & 1) * 64;
    const int lr = ln & 15, lk8 = (ln >> 4) * 8, lk4 = (ln >> 4) * 4;

    f32x4 acc[2][4];
#pragma unroll
    for (int i = 0; i < 2; ++i)
#pragma unroll
        for (int j = 0; j < 4; ++j)
            acc[i][j] = (f32x4){0.f, 0.f, 0.f, 0.f};

#define LOAD_Q(qs, szs, tt) do {                                            \
        _Pragma("unroll")                                                   \
        for (int j = 0; j < 4; ++j) {                                       \
            qs[j]  = *(const ivec4*)(qg + (size_t)j * 32 * (IN_F/2) + (tt) * 32); \
            szs[j] = szp[szb + j * 32 * (IN_F/GROUPSIZE) + ((tt) >> 1)];    \
        }                                                                   \
    } while (0)

#define STAGE_A(tt, buf) do {                                      \
        const _Float16* gp = ag + (size_t)(tt) * 64;               \
        glds16(gp,             &As[buf][wv * 1024]);               \
        glds16(gp + 8 * IN_F,  &As[buf][wv * 1024 + 512]);         \
    } while (0)

#define DQ_STORE(qs, szs, buf) do {                                        \
        _Pragma("unroll")                                                  \
        for (int j = 0; j < 4; ++j)                                        \
            *(half8*)&Bs[buf][swz(r0 + 32 * j, s8 * 8)] = dq8(qs[j], szs[j]); \
    } while (0)

    auto mfma_phase = [&](int buf) {
#pragma unroll
        for (int kk = 0; kk < 2; ++kk) {
            half8 af[2], bf[4];
#pragma unroll
            for (int i = 0; i < 2; ++i)
                af[i] = *(const half8*)&As[buf][swz(wr + i * 16 + lr, kk * 32 + lk8)];
#pragma unroll
            for (int j = 0; j < 4; ++j)
                bf[j] = *(const half8*)&Bs[buf][swz(wc + j * 16 + lr, kk * 32 + lk8)];
#pragma unroll
            for (int i = 0; i < 2; ++i)
#pragma unroll
                for (int j = 0; j < 4; ++j)
                    acc[i][j] = __builtin_amdgcn_mfma_f32_16x16x32_f16(
                        af[i], bf[j], acc[i][j], 0, 0, 0);
        }
    };

    // ---- prologue: regs hold tiles 0,1; LDS buf0 holds tile 0 ----
    ivec4 qA[4], qB[4];
    uint2 szA[4], szB[4];
    LOAD_Q(qA, szA, 0);
    LOAD_Q(qB, szB, 1);
    STAGE_A(0, 0);
    DQ_STORE(qA, szA, 0);
    __syncthreads();

    // ---- main loop: 1 barrier/K-step; B regs 2-deep, A glds 1-deep ----
    for (int t = 0; t < NT; t += 2) {
        {   // iter t (cur = 0)
            const int tl = (t + 2 < NT) ? t + 2 : NT - 1;
            LOAD_Q(qA, szA, tl);
            STAGE_A((t + 1 < NT) ? t + 1 : NT - 1, 1);
            DQ_STORE(qB, szB, 1);
            mfma_phase(0);
            __syncthreads();
        }
        {   // iter t+1 (cur = 1)
            const int tl = (t + 3 < NT) ? t + 3 : NT - 1;
            LOAD_Q(qB, szB, tl);
            STAGE_A((t + 2 < NT) ? t + 2 : NT - 1, 0);
            DQ_STORE(qA, szA, 0);
            mfma_phase(1);
            __syncthreads();
        }
    }

    // ---- epilogue ----
#pragma unroll
    for (int j = 0; j < 4; ++j) {
        const int col = n0 + wc + j * 16 + lr;
        const float bv = bias[col];
#pragma unroll
        for (int i = 0; i < 2; ++i) {
            const int rb = m0 + wr + i * 16 + lk4;
#pragma unroll
            for (int r = 0; r < 4; ++r)
                out[(size_t)(rb + r) * OUT_F + col] = acc[i][j][r] + bv;
        }
    }
#undef LOAD_Q
#undef STAGE_A
#undef DQ_STORE
}

extern "C" void kernel_launch(void* const* d_in, const int* in_sizes, int n_in,
                              void* d_out, int out_size, void* d_ws, size_t ws_size,
                              hipStream_t stream) {
    const float* x      = (const float*)d_in[0];
    const int*   qw     = (const int*)d_in[1];
    const float* scales = (const float*)d_in[2];
    const float* zeros  = (const float*)d_in[3];
    const float* bias   = (const float*)d_in[4];
    float*       out    = (float*)d_out;

    _Float16* x16 = (_Float16*)d_ws;                                   // 4 MB
    uint2*    szp = (uint2*)((char*)d_ws + (size_t)TOKENS * IN_F * 2); // 2.75 MB

    cvt_x_kernel<<<TOKENS * IN_F / (256 * 8), 256, 0, stream>>>(x, x16);
    szpack_kernel<<<(N_GROUPS + 255) / 256, 256, 0, stream>>>(scales, zeros, szp);

    dim3 grid(TOKENS / BM, OUT_F / BN);   // (8 m) x (86 n)
    qlinear_main<<<grid, NTHREADS, 0, stream>>>(x16, qw, szp, bias, out);
}

// Round 4
// 252.068 us; speedup vs baseline: 1.4905x; 1.0118x over previous
//
#include <hip/hip_runtime.h>

#define GROUPSIZE 128
#define IN_F 4096
#define OUT_F 11008
#define TOKENS 512
#define N_GROUPS (OUT_F * IN_F / GROUPSIZE)  // 352256

#define BM 64
#define BN 128
#define BK 64
#define NTHREADS 256
#define NT (IN_F / BK)   // 64 K-steps
#define NTILES_N (OUT_F / BN)   // 86

typedef _Float16 half8  __attribute__((ext_vector_type(8)));
typedef _Float16 half2v __attribute__((ext_vector_type(2)));
typedef float    f32x4  __attribute__((ext_vector_type(4)));
typedef int      ivec4  __attribute__((ext_vector_type(4)));

// halfword-index swizzle within [rows][64]-halfword tile (row = 128 B):
// XOR 16B-granule by row&7 -> frag ds_read_b128 is bank-uniform.
__device__ __forceinline__ int swz(int r, int k) {
    return ((r << 6) + k) ^ ((r & 7) << 3);
}

__device__ __forceinline__ void glds16(const _Float16* g, _Float16* l) {
    __builtin_amdgcn_global_load_lds(
        (const __attribute__((address_space(1))) void*)g,
        (__attribute__((address_space(3))) void*)l, 16, 0, 0);
}

// counted-vmcnt barrier: drain only the 2 A-glds (oldest), keep the 8
// q-loads in flight across the barrier (T4). lgkmcnt(0) publishes ds_writes.
#define WAITBAR8() do {                                                  \
        asm volatile("s_waitcnt vmcnt(8) lgkmcnt(0)" ::: "memory");      \
        __builtin_amdgcn_s_barrier();                                    \
    } while (0)

// ---------- pre-kernel 1: x fp32 -> fp16 (x reused 86x; convert once) ----------
__global__ __launch_bounds__(256)
void cvt_x_kernel(const float* __restrict__ x, _Float16* __restrict__ x16) {
    size_t i = ((size_t)blockIdx.x * 256 + threadIdx.x) * 8;
    f32x4 a = *(const f32x4*)(x + i);
    f32x4 b = *(const f32x4*)(x + i + 4);
    half8 h;
    h[0]=(_Float16)a[0]; h[1]=(_Float16)a[1]; h[2]=(_Float16)a[2]; h[3]=(_Float16)a[3];
    h[4]=(_Float16)b[0]; h[5]=(_Float16)b[1]; h[6]=(_Float16)b[2]; h[7]=(_Float16)b[3];
    *(half8*)(x16 + i) = h;
}

// ---------- pre-kernel 2: pack (S, -(64+z)*S) as duplicated fp16 pairs ----------
__global__ __launch_bounds__(256)
void szpack_kernel(const float* __restrict__ s, const float* __restrict__ z,
                   uint2* __restrict__ szp) {
    int g = blockIdx.x * 256 + threadIdx.x;
    if (g >= N_GROUPS) return;
    _Float16 S = (_Float16)s[g];
    _Float16 B = (_Float16)(-(64.0f + z[g]) * (float)S);
    unsigned short su = __builtin_bit_cast(unsigned short, S);
    unsigned short bu = __builtin_bit_cast(unsigned short, B);
    uint2 r;
    r.x = ((unsigned)su << 16) | su;
    r.y = ((unsigned)bu << 16) | bu;
    szp[g] = r;
}

// dequant 4 int32-bytes (8 nibbles): fp16(64+n) via OR, then one pk_fma each
__device__ __forceinline__ half8 dq8(ivec4 q, uint2 sz) {
    half2v S  = __builtin_bit_cast(half2v, sz.x);
    half2v Bv = __builtin_bit_cast(half2v, sz.y);
    half8 r;
#pragma unroll
    for (int e = 0; e < 4; ++e) {
        unsigned qq = (unsigned)q[e];
        unsigned u = ((qq & 0xF0u) | ((qq << 20) & 0x00F00000u)) | 0x54005400u;
        half2v h = __builtin_bit_cast(half2v, u);
        half2v w = h * S + Bv;          // (64+n)*S - (64+z)*S = (n-z)*S
        r[2*e]   = w[0];                // hi nibble -> even k
        r[2*e+1] = w[1];                // lo nibble -> odd k
    }
    return r;
}

__global__ __launch_bounds__(NTHREADS, 3)
void qlinear_main(const _Float16* __restrict__ x16,
                  const int*   __restrict__ qw,
                  const uint2* __restrict__ szp,
                  const float* __restrict__ bias,
                  float*       __restrict__ out)
{
    __shared__ __align__(16) _Float16 As[2][BM * BK];
    __shared__ __align__(16) _Float16 Bs[2][BN * BK];

    // XCD-local tiling: bid%8 = XCD (dispatch heuristic). Each XCD owns 11
    // n-tiles; the 8 m-blocks of an n-tile share its q-tile in ONE L2.
    const int bid = blockIdx.x;
    const int xcd = bid & 7;
    const int s   = bid >> 3;              // 0..87
    const int n_t = 11 * xcd + (s >> 3);   // 0..87
    const int m_t = s & 7;
    if (n_t >= NTILES_N) return;           // 16 pad blocks idle
    const int n0 = n_t * BN;
    const int m0 = m_t * BM;

    const int tid = threadIdx.x;
    const int wv = tid >> 6, ln = tid & 63;

    // ---- B staging role: 8 consecutive lanes cover 128 contiguous bytes of a
    // row. Thread: 16B segment s8 of rows r0+32j, j=0..3.
    const int s8 = tid & 7;
    const int r0 = tid >> 3;               // 0..31
    const int* qg = qw + (size_t)(n0 + r0) * (IN_F / 2) + s8 * 4;
    const int szb = (n0 + r0) * (IN_F / GROUPSIZE);

    // ---- A staging role (global_load_lds, inverse-swizzled source) ----
    const int ar  = wv * 16 + (ln >> 3);
    const int gsw = (ln & 7) ^ ((ln >> 3) & 7);
    const _Float16* ag = x16 + (size_t)(m0 + ar) * IN_F + gsw * 8;

    // ---- MFMA role: wave (wr,wc) owns 32x64 of the 64x128 tile ----
    const int wr = (wv >> 1) * 32, wc = (wv & 1) * 64;
    const int lr = ln & 15, lk8 = (ln >> 4) * 8, lk4 = (ln >> 4) * 4;

    f32x4 acc[2][4];
#pragma unroll
    for (int i = 0; i < 2; ++i)
#pragma unroll
        for (int j = 0; j < 4; ++j)
            acc[i][j] = (f32x4){0.f, 0.f, 0.f, 0.f};

#define LOAD_Q(qs, szs, tt) do {                                            \
        _Pragma("unroll")                                                   \
        for (int j = 0; j < 4; ++j) {                                       \
            qs[j]  = *(const ivec4*)(qg + (size_t)j * 32 * (IN_F/2) + (tt) * 32); \
            szs[j] = szp[szb + j * 32 * (IN_F/GROUPSIZE) + ((tt) >> 1)];    \
        }                                                                   \
    } while (0)

#define STAGE_A(tt, buf) do {                                      \
        const _Float16* gp = ag + (size_t)(tt) * 64;               \
        glds16(gp,             &As[buf][wv * 1024]);               \
        glds16(gp + 8 * IN_F,  &As[buf][wv * 1024 + 512]);         \
    } while (0)

#define DQ_STORE(qs, szs, buf) do {                                        \
        _Pragma("unroll")                                                  \
        for (int j = 0; j < 4; ++j)                                        \
            *(half8*)&Bs[buf][swz(r0 + 32 * j, s8 * 8)] = dq8(qs[j], szs[j]); \
    } while (0)

    auto mfma_phase = [&](int buf) {
#pragma unroll
        for (int kk = 0; kk < 2; ++kk) {
            half8 af[2], bf[4];
#pragma unroll
            for (int i = 0; i < 2; ++i)
                af[i] = *(const half8*)&As[buf][swz(wr + i * 16 + lr, kk * 32 + lk8)];
#pragma unroll
            for (int j = 0; j < 4; ++j)
                bf[j] = *(const half8*)&Bs[buf][swz(wc + j * 16 + lr, kk * 32 + lk8)];
#pragma unroll
            for (int i = 0; i < 2; ++i)
#pragma unroll
                for (int j = 0; j < 4; ++j)
                    acc[i][j] = __builtin_amdgcn_mfma_f32_16x16x32_f16(
                        af[i], bf[j], acc[i][j], 0, 0, 0);
        }
    };

    // ---- prologue: vmem FIFO = [qA(8), A0(2), qB(8)] ----
    ivec4 qA[4], qB[4];
    uint2 szA[4], szB[4];
    LOAD_Q(qA, szA, 0);          // 8 loads
    STAGE_A(0, 0);               // 2 glds
    LOAD_Q(qB, szB, 1);          // 8 loads
    DQ_STORE(qA, szA, 0);        // compiler waits qA regs (vmcnt(10))
    WAITBAR8();                  // drain A0, keep qB(tile1) in flight

    // ---- main loop: counted-vmcnt pipeline, 1 raw barrier per K-step.
    // Steady state at top: outstanding = [q(t+1) x8].
    for (int t = 0; t < NT; t += 2) {
        {   // compute tile t from buf0
            const int ta = (t + 1 < NT) ? t + 1 : NT - 1;
            const int tq = (t + 2 < NT) ? t + 2 : NT - 1;
            STAGE_A(ta, 1);              // +2 glds (oldest of this body)
            LOAD_Q(qA, szA, tq);         // +8 q loads (stay in flight)
            DQ_STORE(qB, szB, 1);        // waits q(t+1) regs only
            mfma_phase(0);
            WAITBAR8();                  // drain A(t+1); q(t+2) stays out
        }
        {   // compute tile t+1 from buf1
            const int ta = (t + 2 < NT) ? t + 2 : NT - 1;
            const int tq = (t + 3 < NT) ? t + 3 : NT - 1;
            STAGE_A(ta, 0);
            LOAD_Q(qB, szB, tq);
            DQ_STORE(qA, szA, 0);
            mfma_phase(1);
            WAITBAR8();
        }
    }

    // ---- epilogue ----
#pragma unroll
    for (int j = 0; j < 4; ++j) {
        const int col = n0 + wc + j * 16 + lr;
        const float bv = bias[col];
#pragma unroll
        for (int i = 0; i < 2; ++i) {
            const int rb = m0 + wr + i * 16 + lk4;
#pragma unroll
            for (int r = 0; r < 4; ++r)
                out[(size_t)(rb + r) * OUT_F + col] = acc[i][j][r] + bv;
        }
    }
#undef LOAD_Q
#undef STAGE_A
#undef DQ_STORE
}

extern "C" void kernel_launch(void* const* d_in, const int* in_sizes, int n_in,
                              void* d_out, int out_size, void* d_ws, size_t ws_size,
                              hipStream_t stream) {
    const float* x      = (const float*)d_in[0];
    const int*   qw     = (const int*)d_in[1];
    const float* scales = (const float*)d_in[2];
    const float* zeros  = (const float*)d_in[3];
    const float* bias   = (const float*)d_in[4];
    float*       out    = (float*)d_out;

    _Float16* x16 = (_Float16*)d_ws;                                   // 4 MB
    uint2*    szp = (uint2*)((char*)d_ws + (size_t)TOKENS * IN_F * 2); // 2.75 MB

    cvt_x_kernel<<<TOKENS * IN_F / (256 * 8), 256, 0, stream>>>(x, x16);
    szpack_kernel<<<(N_GROUPS + 255) / 256, 256, 0, stream>>>(scales, zeros, szp);

    // padded bijective XCD grouping: 88 n-slot-groups x 8 = 704 blocks
    qlinear_main<<<704, NTHREADS, 0, stream>>>(x16, qw, szp, bias, out);
}